// Round 4
// baseline (143.832 us; speedup 1.0000x reference)
//
#include <hip/hip_runtime.h>

// CurvatureLoss: pred (8,4,1024,1024) fp32 -> scalar loss. target unused.
// Single-wave column-strip sweep, C=2 columns per lane, compile-time register
// rings (zero rotation movs), templated edge masking, no LDS, no barriers.

namespace {
constexpr int H = 1024, W = 1024, B = 8;
constexpr int VALID = 120;            // output cols per wave (64 lanes x 2 - 8)
constexpr int NSTRIPS = 9;            // 9 * 120 = 1080 >= 1024
constexpr int RCHUNK = 32;            // output rows per wave
constexpr int NCHUNKS = H / RCHUNK;   // 32
constexpr int TRIP = RCHUNK + 4;      // 36 = 6 * 6 (ring periods 2,3,6 divide 6)
constexpr size_t HW = (size_t)H * W;
}

// ws layout: float s[24] | unsigned c[24]  (8 batches x 3 fields)
__global__ void zero_ws_kernel(unsigned int* ws) {
    if (threadIdx.x < 48) ws[threadIdx.x] = 0u;
}

__device__ __forceinline__ float2 ld2(const float* p) {
    return *(const float2*)p;
}

template <bool RE>
__device__ __forceinline__ void load_row4(const float* __restrict__ basep, int row,
                                          float2 o[4]) {
    const int rc = RE ? min(max(row, 0), H - 1) : row;  // masked later
    const float* p = basep + (size_t)rc * W;
    o[0] = ld2(p);
    o[1] = ld2(p + HW);
    o[2] = ld2(p + 2 * HW);
    o[3] = ld2(p + 3 * HW);
}

// Softmax over 4 channels for 2 columns; no max-sub (inputs ~N(0,1), no
// overflow: exp(|x|<~6) well within fp32 range). p = {p1, p1+p2, p3}.
__device__ __forceinline__ void softmax_pair(const float2 x[4], bool ok0, bool ok1,
                                             float2 p[3]) {
    const float e0x = __expf(x[0].x), e1x = __expf(x[1].x);
    const float e2x = __expf(x[2].x), e3x = __expf(x[3].x);
    const float e0y = __expf(x[0].y), e1y = __expf(x[1].y);
    const float e2y = __expf(x[2].y), e3y = __expf(x[3].y);
    const float ix = __builtin_amdgcn_rcpf(e0x + e1x + e2x + e3x);
    const float iy = __builtin_amdgcn_rcpf(e0y + e1y + e2y + e3y);
    p[0].x = ok0 ? e1x * ix : 0.f;
    p[0].y = ok1 ? e1y * iy : 0.f;
    p[1].x = ok0 ? (e1x + e2x) * ix : 0.f;
    p[1].y = ok1 ? (e1y + e2y) * iy : 0.f;
    p[2].x = ok0 ? e3x * ix : 0.f;
    p[2].y = ok1 ? e3y * iy : 0.f;
}

template <bool CE, bool RE>
__device__ __forceinline__ void sweep(const float* __restrict__ pred,
                                      float* __restrict__ s_ws,
                                      unsigned int* __restrict__ c_ws,
                                      int b, int strip, int chunk, int lane) {
    const int r0 = chunk * RCHUNK;
    const int li0 = 2 * lane;            // local col index 0..127
    const int col0 = strip * VALID - 4 + li0;
    const int col1 = col0 + 1;
    // Clamped, 8B-aligned address column (values masked when clamped).
    const int colC = CE ? min(max(col0, 0), W - 2) : col0;
    const float* basep = pred + (size_t)b * 4 * HW + colC;

    const bool cOK0 = !CE || ((unsigned)col0 < (unsigned)W);
    const bool cOK1 = !CE || ((unsigned)col1 < (unsigned)W);
    // Valid output local cols are li in [4, 123]  ->  lanes 2..61.
    const bool aOK0 = (li0 >= 4) && (li0 <= 123) && cOK0;
    const bool aOK1 = (li0 + 1 >= 4) && (li0 + 1 <= 123) && cOK1;
    const float aM0 = aOK0 ? 1.f : 0.f;
    const float aM1 = aOK1 ? 1.f : 0.f;
    const float gxpM0 = (!CE || (col0 + 1 < W)) ? 1.f : 0.f;
    const float gxpM1 = (!CE || (col1 + 1 < W)) ? 1.f : 0.f;
    const float gxmM0 = (!CE || (col0 >= 1)) ? 1.f : 0.f;
    const float gxmM1 = (!CE || (col1 >= 1)) ? 1.f : 0.f;

    float2 P[3][3];   // prob ring   [slot][field]
    float2 L[6][3];   // lap ring    [slot][field]
    float2 Rr[3][4];  // raw ring    [slot][channel]  (prefetch depth 2)

    float sacc[3] = {0.f, 0.f, 0.f};
    unsigned int cacc[3] = {0u, 0u, 0u};

    // Prologue: P[1] = prob row r0-3, P[2] = prob row r0-2;
    // Rr[0] = raw row r0-1, Rr[1] = raw row r0.
    {
        float2 t[4];
        load_row4<RE>(basep, r0 - 3, t);
        const bool ok = !RE || ((unsigned)(r0 - 3) < (unsigned)H);
        softmax_pair(t, ok && cOK0, ok && cOK1, P[1]);
        load_row4<RE>(basep, r0 - 2, t);
        const bool ok2 = !RE || ((unsigned)(r0 - 2) < (unsigned)H);
        softmax_pair(t, ok2 && cOK0, ok2 && cOK1, P[2]);
    }
    load_row4<RE>(basep, r0 - 1, Rr[0]);
    load_row4<RE>(basep, r0, Rr[1]);

    auto acc1 = [&](int f, float gx, float gy, float gxp, float gxm,
                    float gyp, float gym, float aM) {
        const float hxx = 2.f * gx - gxp - gxm;
        const float hxy = gxp - gxm;
        const float hyy = 2.f * gy - gyp - gym;
        const float oy = 1.f + gy, ox = 1.f + gx;
        const float numer = hxx * oy * oy - 2.f * hxy * gx * gy + hyy * ox * ox;
        const float xx = 1.f + gx * gx + gy * gy;
        const float rs = __builtin_amdgcn_rsqf(xx);
        const float curv = numer * (0.5f * rs * rs * rs);   // numer / (2 xx^1.5)
        const float negc = fmaxf(-curv, 0.f) * aM;          // finite always
        sacc[f] += negc;
        cacc[f] += (negc != 0.f) ? 1u : 0u;
    };

    for (int m = 0; m < 6; ++m) {
        const int m6 = m * 6;
#pragma unroll
        for (int u = 0; u < 6; ++u) {
            const int i = m6 + u;
            const int y = r0 - 4 + i;
            // 1) prob row y+3 from Rr[u%3] -> P[u%3]
            const bool pok = !RE || ((unsigned)(y + 3) < (unsigned)H);
            softmax_pair(Rr[u % 3], pok && cOK0, pok && cOK1, P[u % 3]);
            // 2) prefetch raw row y+5 -> Rr[(u+2)%3]
            load_row4<RE>(basep, y + 5, Rr[(u + 2) % 3]);
            // 3) lap row y+2 -> L[u], from prob rows y+1,y+2,y+3
            const bool lok = !RE || ((unsigned)(y + 2) < (unsigned)H);
#pragma unroll
            for (int f = 0; f < 3; ++f) {
                const float2 top = P[(u + 1) % 3][f];
                const float2 mid = P[(u + 2) % 3][f];
                const float2 bot = P[u % 3][f];
                const float lft = __shfl(mid.y, lane - 1, 64);
                const float rgt = __shfl(mid.x, lane + 1, 64);
                const float lx = top.x + bot.x + lft + mid.y - 4.f * mid.x;
                const float ly = top.y + bot.y + mid.x + rgt - 4.f * mid.y;
                L[u][f].x = (lok && cOK0) ? lx : 0.f;
                L[u][f].y = (lok && cOK1) ? ly : 0.f;
            }
            // 4) output row y from lap rows y-2..y+2
            if (i >= 4) {
                const float gypM = (!RE || (y + 1 < H)) ? 1.f : 0.f;
                const float gymM = (!RE || (y >= 1)) ? 1.f : 0.f;
#pragma unroll
                for (int f = 0; f < 3; ++f) {
                    const float2 lm2 = L[(u + 2) % 6][f];
                    const float2 lm1 = L[(u + 3) % 6][f];
                    const float2 lc  = L[(u + 4) % 6][f];
                    const float2 lp1 = L[(u + 5) % 6][f];
                    const float2 lp2 = L[u][f];
                    const float A  = __shfl(lc.y, lane - 1, 64);  // lap(x-1)|c0, lap(x-2)|c1
                    const float Bm = __shfl(lc.x, lane - 1, 64);  // lap(x-2)|c0
                    const float Bp = __shfl(lc.x, lane + 1, 64);  // lap(x+2)|c0, lap(x+1)|c1
                    const float Cc = __shfl(lc.y, lane + 1, 64);  // lap(x+2)|c1
                    {   // col 0
                        const float c = lc.x;
                        const float gx = lc.y - A;
                        const float gy = lp1.x - lm1.x;
                        const float gxp = (Bp - c) * gxpM0;
                        const float gxm = (c - Bm) * gxmM0;
                        const float gyp = (lp2.x - c) * gypM;
                        const float gym = (c - lm2.x) * gymM;
                        acc1(f, gx, gy, gxp, gxm, gyp, gym, aM0);
                    }
                    {   // col 1
                        const float c = lc.y;
                        const float gx = Bp - lc.x;
                        const float gy = lp1.y - lm1.y;
                        const float gxp = (Cc - c) * gxpM1;
                        const float gxm = (c - A) * gxmM1;
                        const float gyp = (lp2.y - c) * gypM;
                        const float gym = (c - lm2.y) * gymM;
                        acc1(f, gx, gy, gxp, gxm, gyp, gym, aM1);
                    }
                }
            }
        }
    }

    // Wave reduction + one atomic per field.
#pragma unroll
    for (int f = 0; f < 3; ++f) {
        float v = sacc[f];
        unsigned int c = cacc[f];
        for (int off = 32; off > 0; off >>= 1) {
            v += __shfl_xor(v, off, 64);
            c += __shfl_xor(c, off, 64);
        }
        if (lane == 0) {
            atomicAdd(&s_ws[b * 3 + f], v);
            atomicAdd(&c_ws[b * 3 + f], c);
        }
    }
}

__global__ __launch_bounds__(64)
void curvature_sweep(const float* __restrict__ pred,
                     float* __restrict__ s_ws,
                     unsigned int* __restrict__ c_ws) {
    const int strip = blockIdx.x;
    const int chunk = blockIdx.y;
    const int b = blockIdx.z;
    const int lane = threadIdx.x;
    const bool ce = (strip == 0) || (strip == NSTRIPS - 1);
    const bool re = (chunk == 0) || (chunk == NCHUNKS - 1);
    if (!ce && !re)      sweep<false, false>(pred, s_ws, c_ws, b, strip, chunk, lane);
    else if (ce && !re)  sweep<true, false>(pred, s_ws, c_ws, b, strip, chunk, lane);
    else if (!ce && re)  sweep<false, true>(pred, s_ws, c_ws, b, strip, chunk, lane);
    else                 sweep<true, true>(pred, s_ws, c_ws, b, strip, chunk, lane);
}

__global__ void finalize_kernel(const float* __restrict__ s_ws,
                                const unsigned int* __restrict__ c_ws,
                                float* __restrict__ out) {
    const int lane = threadIdx.x;
    float v = 0.f;
    if (lane < 24) {
        const float s = s_ws[lane];
        const unsigned int c = c_ws[lane];
        v = (c > 0) ? s / (float)c : 0.f;  // max(c,1)==c when c>0
    }
    for (int off = 32; off > 0; off >>= 1) v += __shfl_down(v, off, 64);
    if (lane == 0) out[0] = v;
}

extern "C" void kernel_launch(void* const* d_in, const int* in_sizes, int n_in,
                              void* d_out, int out_size, void* d_ws, size_t ws_size,
                              hipStream_t stream) {
    const float* pred = (const float*)d_in[0];
    float* s_ws = (float*)d_ws;
    unsigned int* c_ws = (unsigned int*)((char*)d_ws + 24 * sizeof(float));
    float* out = (float*)d_out;

    hipLaunchKernelGGL(zero_ws_kernel, dim3(1), dim3(64), 0, stream,
                       (unsigned int*)d_ws);
    dim3 grid(NSTRIPS, NCHUNKS, B);
    hipLaunchKernelGGL(curvature_sweep, grid, dim3(64), 0, stream,
                       pred, s_ws, c_ws);
    hipLaunchKernelGGL(finalize_kernel, dim3(1), dim3(64), 0, stream,
                       s_ws, c_ws, out);
}

// Round 5
// 71.514 us; speedup vs baseline: 2.0113x; 2.0113x over previous
//
#include <hip/hip_runtime.h>

// CurvatureLoss: pred (8,4,1024,1024) fp32 -> scalar loss. target unused.
// C=2 columns/lane register-ring sweep; RCHUNK=8 for high wave count (9216
// waves) so shfl/load/exp latencies are TLP-hidden. 4 waves/block for a
// block-level reduction. No LDS staging, one barrier per block.

namespace {
constexpr int H = 1024, W = 1024, B = 8;
constexpr int VALID = 120;            // output cols per wave (64 lanes x 2 - 8)
constexpr int NSTRIPS = 9;            // 9 * 120 = 1080 >= 1024
constexpr int RCHUNK = 8;             // output rows per wave
constexpr int NCHUNKS = H / RCHUNK;   // 128
constexpr int WPB = 4;                // waves per block
constexpr int NTHREADS = 64 * WPB;
constexpr size_t HW = (size_t)H * W;
}

// ws layout: float s[24] | unsigned c[24]  (8 batches x 3 fields)
__global__ void zero_ws_kernel(unsigned int* ws) {
    if (threadIdx.x < 48) ws[threadIdx.x] = 0u;
}

__device__ __forceinline__ float2 ld2(const float* p) {
    return *(const float2*)p;
}

template <bool RE>
__device__ __forceinline__ void load_row4(const float* __restrict__ basep, int row,
                                          float2 o[4]) {
    const int rc = RE ? min(max(row, 0), H - 1) : row;  // masked later
    const float* p = basep + (size_t)rc * W;
    o[0] = ld2(p);
    o[1] = ld2(p + HW);
    o[2] = ld2(p + 2 * HW);
    o[3] = ld2(p + 3 * HW);
}

// Softmax over 4 channels for 2 columns; no max-sub (inputs ~N(0,1): no
// overflow risk). p = {p1, p1+p2, p3}. Masked to 0 where !ok (CE only).
template <bool CE>
__device__ __forceinline__ void softmax_pair(const float2 x[4], bool ok0, bool ok1,
                                             float2 p[3]) {
    const float e0x = __expf(x[0].x), e1x = __expf(x[1].x);
    const float e2x = __expf(x[2].x), e3x = __expf(x[3].x);
    const float e0y = __expf(x[0].y), e1y = __expf(x[1].y);
    const float e2y = __expf(x[2].y), e3y = __expf(x[3].y);
    const float ix = __builtin_amdgcn_rcpf(e0x + e1x + e2x + e3x);
    const float iy = __builtin_amdgcn_rcpf(e0y + e1y + e2y + e3y);
    if (CE) {
        p[0].x = ok0 ? e1x * ix : 0.f;
        p[0].y = ok1 ? e1y * iy : 0.f;
        p[1].x = ok0 ? (e1x + e2x) * ix : 0.f;
        p[1].y = ok1 ? (e1y + e2y) * iy : 0.f;
        p[2].x = ok0 ? e3x * ix : 0.f;
        p[2].y = ok1 ? e3y * iy : 0.f;
    } else {
        p[0].x = e1x * ix;            p[0].y = e1y * iy;
        p[1].x = (e1x + e2x) * ix;    p[1].y = (e1y + e2y) * iy;
        p[2].x = e3x * ix;            p[2].y = e3y * iy;
    }
}

template <bool CE, bool RE>
__device__ __forceinline__ void sweep(const float* __restrict__ pred,
                                      int b, int strip, int chunk, int lane,
                                      float sacc[3], unsigned int cacc[3]) {
    const int r0 = chunk * RCHUNK;
    const int li0 = 2 * lane;            // local col index 0..127
    const int col0 = strip * VALID - 4 + li0;
    const int col1 = col0 + 1;
    const int colC = CE ? min(max(col0, 0), W - 2) : col0;  // 8B-aligned clamp
    const float* basep = pred + (size_t)b * 4 * HW + colC;

    const bool cOK0 = !CE || ((unsigned)col0 < (unsigned)W);
    const bool cOK1 = !CE || ((unsigned)col1 < (unsigned)W);
    // Valid output local cols: li in [4, 123] -> lanes 2..61.
    const bool aOK0 = (li0 >= 4) && (li0 <= 123) && cOK0;
    const bool aOK1 = (li0 + 1 >= 4) && (li0 + 1 <= 123) && cOK1;
    const float gxpM0 = (!CE || (col0 + 1 < W)) ? 1.f : 0.f;
    const float gxpM1 = (!CE || (col1 + 1 < W)) ? 1.f : 0.f;
    const float gxmM0 = (!CE || (col0 >= 1)) ? 1.f : 0.f;
    const float gxmM1 = (!CE || (col1 >= 1)) ? 1.f : 0.f;

    float2 P[3][3];   // prob ring [slot = i%3][field]
    float2 L[6][3];   // lap ring  [slot = i%6][field]
    float2 Rr[2][4];  // raw ring  [slot = i%2][channel], prefetch depth 2

    // Prologue: P[1] = prob row r0-3, P[2] = prob row r0-2,
    //           Rr[0] = raw row r0-1, Rr[1] = raw row r0.
    {
        float2 t[4];
        load_row4<RE>(basep, r0 - 3, t);
        const bool ok = !RE || ((unsigned)(r0 - 3) < (unsigned)H);
        softmax_pair<CE || RE>(t, ok && cOK0, ok && cOK1, P[1]);
        load_row4<RE>(basep, r0 - 2, t);
        const bool ok2 = !RE || ((unsigned)(r0 - 2) < (unsigned)H);
        softmax_pair<CE || RE>(t, ok2 && cOK0, ok2 && cOK1, P[2]);
    }
    load_row4<RE>(basep, r0 - 1, Rr[0]);
    load_row4<RE>(basep, r0, Rr[1]);

    auto acc1 = [&](int f, float gx, float gy, float gxp, float gxm,
                    float gyp, float gym, bool aOK) {
        const float hxx = 2.f * gx - gxp - gxm;
        const float hxy = gxp - gxm;
        const float hyy = 2.f * gy - gyp - gym;
        const float oy = 1.f + gy, ox = 1.f + gx;
        const float numer = hxx * oy * oy - 2.f * hxy * gx * gy + hyy * ox * ox;
        const float xx = 1.f + gx * gx + gy * gy;
        const float rs = __builtin_amdgcn_rsqf(xx);
        const float curv = numer * (0.5f * rs * rs * rs);   // numer/(2 xx^1.5)
        const float negc = aOK ? fmaxf(-curv, 0.f) : 0.f;
        sacc[f] += negc;
        cacc[f] += (negc != 0.f) ? 1u : 0u;
    };

    for (int m = 0; m < 2; ++m) {
#pragma unroll
        for (int u = 0; u < 6; ++u) {
            const int y = r0 - 4 + m * 6 + u;     // output row of this step
            // 1) prob row y+3 from Rr[u%2] -> P[u%3]
            const bool pok = !RE || ((unsigned)(y + 3) < (unsigned)H);
            softmax_pair<CE || RE>(Rr[u % 2], pok && cOK0, pok && cOK1, P[u % 3]);
            // 2) prefetch raw row y+5 -> Rr[u%2] (consumed at step i+2)
            load_row4<RE>(basep, y + 5, Rr[u % 2]);
            // 3) lap row y+2 -> L[u%6], from prob rows y+1, y+2, y+3
            const bool lok = !RE || ((unsigned)(y + 2) < (unsigned)H);
#pragma unroll
            for (int f = 0; f < 3; ++f) {
                const float2 top = P[(u + 1) % 3][f];
                const float2 mid = P[(u + 2) % 3][f];
                const float2 bot = P[u % 3][f];
                const float lft = __shfl(mid.y, lane - 1, 64);
                const float rgt = __shfl(mid.x, lane + 1, 64);
                const float lx = top.x + bot.x + lft + mid.y - 4.f * mid.x;
                const float ly = top.y + bot.y + mid.x + rgt - 4.f * mid.y;
                if (CE || RE) {
                    L[u][f].x = (lok && cOK0) ? lx : 0.f;
                    L[u][f].y = (lok && cOK1) ? ly : 0.f;
                } else {
                    L[u][f].x = lx;
                    L[u][f].y = ly;
                }
            }
            // 4) output row y from lap rows y-2..y+2 (skip 4 prologue steps)
            if (m > 0 || u >= 4) {
                const float gypM = (!RE || (y + 1 < H)) ? 1.f : 0.f;
                const float gymM = (!RE || (y >= 1)) ? 1.f : 0.f;
#pragma unroll
                for (int f = 0; f < 3; ++f) {
                    const float2 lm2 = L[(u + 2) % 6][f];
                    const float2 lm1 = L[(u + 3) % 6][f];
                    const float2 lc  = L[(u + 4) % 6][f];
                    const float2 lp1 = L[(u + 5) % 6][f];
                    const float2 lp2 = L[u % 6][f];
                    const float A  = __shfl(lc.y, lane - 1, 64);  // lap(li-1)
                    const float Bm = __shfl(lc.x, lane - 1, 64);  // lap(li-2)
                    const float Bp = __shfl(lc.x, lane + 1, 64);  // lap(li+2)
                    const float Cc = __shfl(lc.y, lane + 1, 64);  // lap(li+3)
                    {   // col 0
                        const float c = lc.x;
                        const float gx = lc.y - A;
                        const float gy = lp1.x - lm1.x;
                        const float gxp = (Bp - c) * gxpM0;
                        const float gxm = (c - Bm) * gxmM0;
                        const float gyp = (lp2.x - c) * gypM;
                        const float gym = (c - lm2.x) * gymM;
                        acc1(f, gx, gy, gxp, gxm, gyp, gym, aOK0);
                    }
                    {   // col 1
                        const float c = lc.y;
                        const float gx = Bp - lc.x;
                        const float gy = lp1.y - lm1.y;
                        const float gxp = (Cc - c) * gxpM1;
                        const float gxm = (c - A) * gxmM1;
                        const float gyp = (lp2.y - c) * gypM;
                        const float gym = (c - lm2.y) * gymM;
                        acc1(f, gx, gy, gxp, gxm, gyp, gym, aOK1);
                    }
                }
            }
        }
    }
}

__global__ __launch_bounds__(NTHREADS)
void curvature_sweep(const float* __restrict__ pred,
                     float* __restrict__ s_ws,
                     unsigned int* __restrict__ c_ws) {
    __shared__ float redS[3][WPB];
    __shared__ unsigned int redC[3][WPB];

    const int strip = blockIdx.x;
    const int b = blockIdx.z;
    const int tid = threadIdx.x;
    const int wv = tid >> 6, lane = tid & 63;
    const int chunk = blockIdx.y * WPB + wv;

    const bool ce = (strip == 0) || (strip == NSTRIPS - 1);
    const bool re = (chunk == 0) || (chunk == NCHUNKS - 1);

    float sacc[3] = {0.f, 0.f, 0.f};
    unsigned int cacc[3] = {0u, 0u, 0u};
    if (!ce && !re)      sweep<false, false>(pred, b, strip, chunk, lane, sacc, cacc);
    else if (ce && !re)  sweep<true, false>(pred, b, strip, chunk, lane, sacc, cacc);
    else if (!ce && re)  sweep<false, true>(pred, b, strip, chunk, lane, sacc, cacc);
    else                 sweep<true, true>(pred, b, strip, chunk, lane, sacc, cacc);

    // Wave reduction -> LDS -> one atomic pair per (block, field).
#pragma unroll
    for (int f = 0; f < 3; ++f) {
        float v = sacc[f];
        unsigned int c = cacc[f];
        for (int off = 32; off > 0; off >>= 1) {
            v += __shfl_xor(v, off, 64);
            c += __shfl_xor(c, off, 64);
        }
        if (lane == 0) { redS[f][wv] = v; redC[f][wv] = c; }
    }
    __syncthreads();
    if (tid < 3) {
        float v = 0.f;
        unsigned int c = 0;
        for (int w2 = 0; w2 < WPB; ++w2) { v += redS[tid][w2]; c += redC[tid][w2]; }
        atomicAdd(&s_ws[b * 3 + tid], v);
        atomicAdd(&c_ws[b * 3 + tid], c);
    }
}

__global__ void finalize_kernel(const float* __restrict__ s_ws,
                                const unsigned int* __restrict__ c_ws,
                                float* __restrict__ out) {
    const int lane = threadIdx.x;
    float v = 0.f;
    if (lane < 24) {
        const float s = s_ws[lane];
        const unsigned int c = c_ws[lane];
        v = (c > 0) ? s / (float)c : 0.f;  // max(c,1)==c when c>0
    }
    for (int off = 32; off > 0; off >>= 1) v += __shfl_down(v, off, 64);
    if (lane == 0) out[0] = v;
}

extern "C" void kernel_launch(void* const* d_in, const int* in_sizes, int n_in,
                              void* d_out, int out_size, void* d_ws, size_t ws_size,
                              hipStream_t stream) {
    const float* pred = (const float*)d_in[0];
    float* s_ws = (float*)d_ws;
    unsigned int* c_ws = (unsigned int*)((char*)d_ws + 24 * sizeof(float));
    float* out = (float*)d_out;

    hipLaunchKernelGGL(zero_ws_kernel, dim3(1), dim3(64), 0, stream,
                       (unsigned int*)d_ws);
    dim3 grid(NSTRIPS, NCHUNKS / WPB, B);
    hipLaunchKernelGGL(curvature_sweep, grid, dim3(NTHREADS), 0, stream,
                       pred, s_ws, c_ws);
    hipLaunchKernelGGL(finalize_kernel, dim3(1), dim3(64), 0, stream,
                       s_ws, c_ws, out);
}

// Round 6
// 68.429 us; speedup vs baseline: 2.1019x; 1.0451x over previous
//
#include <hip/hip_runtime.h>

// CurvatureLoss: pred (8,4,1024,1024) fp32 -> scalar loss. target unused.
// C=2 columns/lane register-ring sweep, RCHUNK=8 (9216 waves). All cross-lane
// exchanges are +-1 lane -> DPP wave_shr1/wave_shl1 (full-rate VALU, no DS
// pipe, no lgkmcnt stalls). No LDS staging; one barrier per block.

namespace {
constexpr int H = 1024, W = 1024, B = 8;
constexpr int VALID = 120;            // output cols per wave (64 lanes x 2 - 8)
constexpr int NSTRIPS = 9;            // 9 * 120 = 1080 >= 1024
constexpr int RCHUNK = 8;             // output rows per wave
constexpr int NCHUNKS = H / RCHUNK;   // 128
constexpr int WPB = 4;                // waves per block
constexpr int NTHREADS = 64 * WPB;
constexpr size_t HW = (size_t)H * W;
}

// DPP cross-lane: get left/right neighbor's value. Out-of-range lane -> 0.
__device__ __forceinline__ float dpp_left(float x) {   // lane n <- lane n-1
    return __builtin_bit_cast(float,
        __builtin_amdgcn_update_dpp(0, __builtin_bit_cast(int, x),
                                    0x138 /*wave_shr1*/, 0xf, 0xf, false));
}
__device__ __forceinline__ float dpp_right(float x) {  // lane n <- lane n+1
    return __builtin_bit_cast(float,
        __builtin_amdgcn_update_dpp(0, __builtin_bit_cast(int, x),
                                    0x130 /*wave_shl1*/, 0xf, 0xf, false));
}

// ws layout: float s[24] | unsigned c[24]  (8 batches x 3 fields)
__global__ void zero_ws_kernel(unsigned int* ws) {
    if (threadIdx.x < 48) ws[threadIdx.x] = 0u;
}

__device__ __forceinline__ float2 ld2(const float* p) {
    return *(const float2*)p;
}

template <bool RE>
__device__ __forceinline__ void load_row4(const float* __restrict__ basep, int row,
                                          float2 o[4]) {
    const int rc = RE ? min(max(row, 0), H - 1) : row;  // masked later
    const float* p = basep + (size_t)rc * W;
    o[0] = ld2(p);
    o[1] = ld2(p + HW);
    o[2] = ld2(p + 2 * HW);
    o[3] = ld2(p + 3 * HW);
}

// Softmax over 4 channels for 2 columns; no max-sub (inputs ~N(0,1): no
// overflow risk). p = {p1, p1+p2, p3}. Masked to 0 where !ok (edge only).
template <bool CE>
__device__ __forceinline__ void softmax_pair(const float2 x[4], bool ok0, bool ok1,
                                             float2 p[3]) {
    const float e0x = __expf(x[0].x), e1x = __expf(x[1].x);
    const float e2x = __expf(x[2].x), e3x = __expf(x[3].x);
    const float e0y = __expf(x[0].y), e1y = __expf(x[1].y);
    const float e2y = __expf(x[2].y), e3y = __expf(x[3].y);
    const float ix = __builtin_amdgcn_rcpf(e0x + e1x + e2x + e3x);
    const float iy = __builtin_amdgcn_rcpf(e0y + e1y + e2y + e3y);
    if (CE) {
        p[0].x = ok0 ? e1x * ix : 0.f;
        p[0].y = ok1 ? e1y * iy : 0.f;
        p[1].x = ok0 ? (e1x + e2x) * ix : 0.f;
        p[1].y = ok1 ? (e1y + e2y) * iy : 0.f;
        p[2].x = ok0 ? e3x * ix : 0.f;
        p[2].y = ok1 ? e3y * iy : 0.f;
    } else {
        p[0].x = e1x * ix;            p[0].y = e1y * iy;
        p[1].x = (e1x + e2x) * ix;    p[1].y = (e1y + e2y) * iy;
        p[2].x = e3x * ix;            p[2].y = e3y * iy;
    }
}

template <bool CE, bool RE>
__device__ __forceinline__ void sweep(const float* __restrict__ pred,
                                      int b, int strip, int chunk, int lane,
                                      float sacc[3], unsigned int cacc[3]) {
    const int r0 = chunk * RCHUNK;
    const int li0 = 2 * lane;            // local col index 0..127
    const int col0 = strip * VALID - 4 + li0;
    const int col1 = col0 + 1;
    const int colC = CE ? min(max(col0, 0), W - 2) : col0;  // 8B-aligned clamp
    const float* basep = pred + (size_t)b * 4 * HW + colC;

    const bool cOK0 = !CE || ((unsigned)col0 < (unsigned)W);
    const bool cOK1 = !CE || ((unsigned)col1 < (unsigned)W);
    // Valid output local cols: li in [4, 123] -> lanes 2..61.
    const bool aOK0 = (li0 >= 4) && (li0 <= 123) && cOK0;
    const bool aOK1 = (li0 + 1 >= 4) && (li0 + 1 <= 123) && cOK1;
    const float gxpM0 = (!CE || (col0 + 1 < W)) ? 1.f : 0.f;
    const float gxpM1 = (!CE || (col1 + 1 < W)) ? 1.f : 0.f;
    const float gxmM0 = (!CE || (col0 >= 1)) ? 1.f : 0.f;
    const float gxmM1 = (!CE || (col1 >= 1)) ? 1.f : 0.f;

    float2 P[3][3];   // prob ring [slot = i%3][field]
    float2 L[6][3];   // lap ring  [slot = i%6][field]
    float2 Rr[2][4];  // raw ring  [slot = i%2][channel], prefetch depth 2

    // Prologue: P[1] = prob row r0-3, P[2] = prob row r0-2,
    //           Rr[0] = raw row r0-1, Rr[1] = raw row r0.
    {
        float2 t[4];
        load_row4<RE>(basep, r0 - 3, t);
        const bool ok = !RE || ((unsigned)(r0 - 3) < (unsigned)H);
        softmax_pair<CE || RE>(t, ok && cOK0, ok && cOK1, P[1]);
        load_row4<RE>(basep, r0 - 2, t);
        const bool ok2 = !RE || ((unsigned)(r0 - 2) < (unsigned)H);
        softmax_pair<CE || RE>(t, ok2 && cOK0, ok2 && cOK1, P[2]);
    }
    load_row4<RE>(basep, r0 - 1, Rr[0]);
    load_row4<RE>(basep, r0, Rr[1]);

    auto acc1 = [&](int f, float gx, float gy, float gxp, float gxm,
                    float gyp, float gym, bool aOK) {
        const float hxx = 2.f * gx - gxp - gxm;
        const float hxy = gxp - gxm;
        const float hyy = 2.f * gy - gyp - gym;
        const float oy = 1.f + gy, ox = 1.f + gx;
        const float numer = hxx * oy * oy - 2.f * hxy * gx * gy + hyy * ox * ox;
        const float xx = 1.f + gx * gx + gy * gy;
        const float rs = __builtin_amdgcn_rsqf(xx);
        const float curv = numer * (0.5f * rs * rs * rs);   // numer/(2 xx^1.5)
        const float negc = aOK ? fmaxf(-curv, 0.f) : 0.f;
        sacc[f] += negc;
        cacc[f] += (negc != 0.f) ? 1u : 0u;
    };

    for (int m = 0; m < 2; ++m) {
#pragma unroll
        for (int u = 0; u < 6; ++u) {
            const int y = r0 - 4 + m * 6 + u;     // output row of this step
            // 1) prob row y+3 from Rr[u%2] -> P[u%3]
            const bool pok = !RE || ((unsigned)(y + 3) < (unsigned)H);
            softmax_pair<CE || RE>(Rr[u % 2], pok && cOK0, pok && cOK1, P[u % 3]);
            // 2) prefetch raw row y+5 -> Rr[u%2] (consumed at step i+2)
            load_row4<RE>(basep, y + 5, Rr[u % 2]);
            // 3) lap row y+2 -> L[u%6], from prob rows y+1, y+2, y+3
            const bool lok = !RE || ((unsigned)(y + 2) < (unsigned)H);
#pragma unroll
            for (int f = 0; f < 3; ++f) {
                const float2 top = P[(u + 1) % 3][f];
                const float2 mid = P[(u + 2) % 3][f];
                const float2 bot = P[u % 3][f];
                const float lft = dpp_left(mid.y);    // prob(li0-1)
                const float rgt = dpp_right(mid.x);   // prob(li0+2)
                const float lx = top.x + bot.x + lft + mid.y - 4.f * mid.x;
                const float ly = top.y + bot.y + mid.x + rgt - 4.f * mid.y;
                if (CE || RE) {
                    L[u][f].x = (lok && cOK0) ? lx : 0.f;
                    L[u][f].y = (lok && cOK1) ? ly : 0.f;
                } else {
                    L[u][f].x = lx;
                    L[u][f].y = ly;
                }
            }
            // 4) output row y from lap rows y-2..y+2 (skip 4 prologue steps)
            if (m > 0 || u >= 4) {
                const float gypM = (!RE || (y + 1 < H)) ? 1.f : 0.f;
                const float gymM = (!RE || (y >= 1)) ? 1.f : 0.f;
#pragma unroll
                for (int f = 0; f < 3; ++f) {
                    const float2 lm2 = L[(u + 2) % 6][f];
                    const float2 lm1 = L[(u + 3) % 6][f];
                    const float2 lc  = L[(u + 4) % 6][f];
                    const float2 lp1 = L[(u + 5) % 6][f];
                    const float2 lp2 = L[u % 6][f];
                    const float A  = dpp_left(lc.y);   // lap(li0-1)
                    const float Bm = dpp_left(lc.x);   // lap(li0-2)
                    const float Bp = dpp_right(lc.x);  // lap(li0+2)
                    const float Cc = dpp_right(lc.y);  // lap(li0+3)
                    {   // col 0
                        const float c = lc.x;
                        const float gx = lc.y - A;
                        const float gy = lp1.x - lm1.x;
                        const float gxp = (Bp - c) * gxpM0;
                        const float gxm = (c - Bm) * gxmM0;
                        const float gyp = (lp2.x - c) * gypM;
                        const float gym = (c - lm2.x) * gymM;
                        acc1(f, gx, gy, gxp, gxm, gyp, gym, aOK0);
                    }
                    {   // col 1
                        const float c = lc.y;
                        const float gx = Bp - lc.x;
                        const float gy = lp1.y - lm1.y;
                        const float gxp = (Cc - c) * gxpM1;
                        const float gxm = (c - A) * gxmM1;
                        const float gyp = (lp2.y - c) * gypM;
                        const float gym = (c - lm2.y) * gymM;
                        acc1(f, gx, gy, gxp, gxm, gyp, gym, aOK1);
                    }
                }
            }
        }
    }
}

__global__ __launch_bounds__(NTHREADS)
void curvature_sweep(const float* __restrict__ pred,
                     float* __restrict__ s_ws,
                     unsigned int* __restrict__ c_ws) {
    __shared__ float redS[3][WPB];
    __shared__ unsigned int redC[3][WPB];

    const int strip = blockIdx.x;
    const int b = blockIdx.z;
    const int tid = threadIdx.x;
    const int wv = tid >> 6, lane = tid & 63;
    const int chunk = blockIdx.y * WPB + wv;

    const bool ce = (strip == 0) || (strip == NSTRIPS - 1);
    const bool re = (chunk == 0) || (chunk == NCHUNKS - 1);

    float sacc[3] = {0.f, 0.f, 0.f};
    unsigned int cacc[3] = {0u, 0u, 0u};
    if (!ce && !re)      sweep<false, false>(pred, b, strip, chunk, lane, sacc, cacc);
    else if (ce && !re)  sweep<true, false>(pred, b, strip, chunk, lane, sacc, cacc);
    else if (!ce && re)  sweep<false, true>(pred, b, strip, chunk, lane, sacc, cacc);
    else                 sweep<true, true>(pred, b, strip, chunk, lane, sacc, cacc);

    // Wave reduction -> LDS -> one atomic pair per (block, field).
#pragma unroll
    for (int f = 0; f < 3; ++f) {
        float v = sacc[f];
        unsigned int c = cacc[f];
        for (int off = 32; off > 0; off >>= 1) {
            v += __shfl_xor(v, off, 64);
            c += __shfl_xor(c, off, 64);
        }
        if (lane == 0) { redS[f][wv] = v; redC[f][wv] = c; }
    }
    __syncthreads();
    if (tid < 3) {
        float v = 0.f;
        unsigned int c = 0;
        for (int w2 = 0; w2 < WPB; ++w2) { v += redS[tid][w2]; c += redC[tid][w2]; }
        atomicAdd(&s_ws[b * 3 + tid], v);
        atomicAdd(&c_ws[b * 3 + tid], c);
    }
}

__global__ void finalize_kernel(const float* __restrict__ s_ws,
                                const unsigned int* __restrict__ c_ws,
                                float* __restrict__ out) {
    const int lane = threadIdx.x;
    float v = 0.f;
    if (lane < 24) {
        const float s = s_ws[lane];
        const unsigned int c = c_ws[lane];
        v = (c > 0) ? s / (float)c : 0.f;  // max(c,1)==c when c>0
    }
    for (int off = 32; off > 0; off >>= 1) v += __shfl_down(v, off, 64);
    if (lane == 0) out[0] = v;
}

extern "C" void kernel_launch(void* const* d_in, const int* in_sizes, int n_in,
                              void* d_out, int out_size, void* d_ws, size_t ws_size,
                              hipStream_t stream) {
    const float* pred = (const float*)d_in[0];
    float* s_ws = (float*)d_ws;
    unsigned int* c_ws = (unsigned int*)((char*)d_ws + 24 * sizeof(float));
    float* out = (float*)d_out;

    hipLaunchKernelGGL(zero_ws_kernel, dim3(1), dim3(64), 0, stream,
                       (unsigned int*)d_ws);
    dim3 grid(NSTRIPS, NCHUNKS / WPB, B);
    hipLaunchKernelGGL(curvature_sweep, grid, dim3(NTHREADS), 0, stream,
                       pred, s_ws, c_ws);
    hipLaunchKernelGGL(finalize_kernel, dim3(1), dim3(64), 0, stream,
                       s_ws, c_ws, out);
}

// Round 7
// 56.422 us; speedup vs baseline: 2.5492x; 1.2128x over previous
//
#include <hip/hip_runtime.h>

// CurvatureLoss: pred (8,4,1024,1024) fp32 -> scalar loss. target unused.
// C=2 cols/lane register-ring sweep, RCHUNK=16 (4608 waves), ring periods
// {P:5, L:5, Rr:2} with unroll-10 (compile-time ring indices). All per-field
// math on <2 x float> ext-vectors -> v_pk_{fma,add,mul}_f32 packed fp32.
// Cross-lane via DPP wave_shr1/shl1. No LDS staging; one barrier per block.

namespace {
constexpr int H = 1024, W = 1024, B = 8;
constexpr int VALID = 120;            // output cols per wave (64 lanes x 2 - 8)
constexpr int NSTRIPS = 9;            // 9 * 120 = 1080 >= 1024
constexpr int RCHUNK = 16;            // output rows per wave
constexpr int NCHUNKS = H / RCHUNK;   // 64
constexpr int WPB = 4;                // waves per block
constexpr int NTHREADS = 64 * WPB;
constexpr size_t HW = (size_t)H * W;
}

using v2f = __attribute__((ext_vector_type(2))) float;

__device__ __forceinline__ v2f mk2(float a, float b) {
    v2f r; r.x = a; r.y = b; return r;
}

// DPP cross-lane: neighbor lane's value. Out-of-range lane -> 0 (unused lanes).
__device__ __forceinline__ float dpp_left(float x) {   // lane n <- lane n-1
    return __builtin_bit_cast(float,
        __builtin_amdgcn_update_dpp(0, __builtin_bit_cast(int, x),
                                    0x138 /*wave_shr1*/, 0xf, 0xf, false));
}
__device__ __forceinline__ float dpp_right(float x) {  // lane n <- lane n+1
    return __builtin_bit_cast(float,
        __builtin_amdgcn_update_dpp(0, __builtin_bit_cast(int, x),
                                    0x130 /*wave_shl1*/, 0xf, 0xf, false));
}

// ws layout: float s[24] | unsigned c[24]  (8 batches x 3 fields)
__global__ void zero_ws_kernel(unsigned int* ws) {
    if (threadIdx.x < 48) ws[threadIdx.x] = 0u;
}

template <bool RE>
__device__ __forceinline__ void load_row4(const float* __restrict__ basep, int row,
                                          v2f o[4]) {
    const int rc = RE ? min(max(row, 0), H - 1) : row;  // masked later
    const float* p = basep + (size_t)rc * W;
    o[0] = *(const v2f*)p;
    o[1] = *(const v2f*)(p + HW);
    o[2] = *(const v2f*)(p + 2 * HW);
    o[3] = *(const v2f*)(p + 3 * HW);
}

// Softmax over 4 channels for 2 columns; no max-sub (inputs ~N(0,1): no
// overflow risk). p = {p1, p1+p2, p3}. Masked to 0 where !ok (edges only).
template <bool EDGE>
__device__ __forceinline__ void softmax_pair(const v2f x[4], bool ok0, bool ok1,
                                             v2f p[3]) {
    const float e0x = __expf(x[0].x), e1x = __expf(x[1].x);
    const float e2x = __expf(x[2].x), e3x = __expf(x[3].x);
    const float e0y = __expf(x[0].y), e1y = __expf(x[1].y);
    const float e2y = __expf(x[2].y), e3y = __expf(x[3].y);
    const float ix = __builtin_amdgcn_rcpf(e0x + e1x + e2x + e3x);
    const float iy = __builtin_amdgcn_rcpf(e0y + e1y + e2y + e3y);
    if (EDGE) {
        p[0] = mk2(ok0 ? e1x * ix : 0.f,          ok1 ? e1y * iy : 0.f);
        p[1] = mk2(ok0 ? (e1x + e2x) * ix : 0.f,  ok1 ? (e1y + e2y) * iy : 0.f);
        p[2] = mk2(ok0 ? e3x * ix : 0.f,          ok1 ? e3y * iy : 0.f);
    } else {
        p[0] = mk2(e1x * ix,          e1y * iy);
        p[1] = mk2((e1x + e2x) * ix,  (e1y + e2y) * iy);
        p[2] = mk2(e3x * ix,          e3y * iy);
    }
}

template <bool CE, bool RE>
__device__ __forceinline__ void sweep(const float* __restrict__ pred,
                                      int b, int strip, int chunk, int lane,
                                      v2f sacc[3], unsigned int cacc0[3],
                                      unsigned int cacc1[3]) {
    const int r0 = chunk * RCHUNK;
    const int li0 = 2 * lane;            // local col index 0..127
    const int col0 = strip * VALID - 4 + li0;
    const int col1 = col0 + 1;
    const int colC = CE ? min(max(col0, 0), W - 2) : col0;  // even -> 8B aligned
    const float* basep = pred + (size_t)b * 4 * HW + colC;

    const bool cOK0 = !CE || ((unsigned)col0 < (unsigned)W);
    const bool cOK1 = !CE || ((unsigned)col1 < (unsigned)W);
    // Valid output local cols: li in [4, 123] -> lanes 2..61.
    const bool aOK0 = (li0 >= 4) && (li0 <= 123) && cOK0;
    const bool aOK1 = (li0 + 1 >= 4) && (li0 + 1 <= 123) && cOK1;
    const v2f aM = mk2(aOK0 ? 1.f : 0.f, aOK1 ? 1.f : 0.f);
    const v2f gxpM = mk2((!CE || (col0 + 1 < W)) ? 1.f : 0.f,
                         (!CE || (col1 + 1 < W)) ? 1.f : 0.f);
    const v2f gxmM = mk2((!CE || (col0 >= 1)) ? 1.f : 0.f,
                         (!CE || (col1 >= 1)) ? 1.f : 0.f);

    v2f P[5][3];   // prob ring [slot = i%5][field]
    v2f L[5][3];   // lap ring  [slot = i%5][field]
    v2f Rr[2][4];  // raw ring  [slot = i%2][channel], prefetch depth 2

    // Prologue: P[3] = prob row r0-3, P[4] = prob row r0-2,
    //           Rr[0] = raw row r0-1, Rr[1] = raw row r0.
    {
        v2f t[4];
        load_row4<RE>(basep, r0 - 3, t);
        const bool ok = !RE || ((unsigned)(r0 - 3) < (unsigned)H);
        softmax_pair<CE || RE>(t, ok && cOK0, ok && cOK1, P[3]);
        load_row4<RE>(basep, r0 - 2, t);
        const bool ok2 = !RE || ((unsigned)(r0 - 2) < (unsigned)H);
        softmax_pair<CE || RE>(t, ok2 && cOK0, ok2 && cOK1, P[4]);
    }
    load_row4<RE>(basep, r0 - 1, Rr[0]);
    load_row4<RE>(basep, r0, Rr[1]);

    for (int m = 0; m < 2; ++m) {
#pragma unroll
        for (int u = 0; u < 10; ++u) {
            const int y = r0 - 4 + m * 10 + u;    // output row of this step
            // 1) prob row y+3 from Rr[u%2] -> P[u%5]
            const bool pok = !RE || ((unsigned)(y + 3) < (unsigned)H);
            softmax_pair<CE || RE>(Rr[u % 2], pok && cOK0, pok && cOK1, P[u % 5]);
            // 2) prefetch raw row y+5 -> Rr[u%2] (consumed at step i+2)
            load_row4<RE>(basep, y + 5, Rr[u % 2]);
            // 3) lap row y+2 -> L[u%5] from prob rows y+1 (P[(u+3)%5]),
            //    y+2 (P[(u+4)%5]), y+3 (P[u%5]).
            const bool lok = !RE || ((unsigned)(y + 2) < (unsigned)H);
#pragma unroll
            for (int f = 0; f < 3; ++f) {
                const v2f top = P[(u + 3) % 5][f];
                const v2f mid = P[(u + 4) % 5][f];
                const v2f bot = P[u % 5][f];
                const float lft = dpp_left(mid.y);    // prob(li0-1)
                const float rgt = dpp_right(mid.x);   // prob(li0+2)
                const v2f horiz = mk2(lft, mid.x) + mk2(mid.y, rgt);
                const v2f l = top + bot + horiz - 4.f * mid;
                if (CE || RE) {
                    L[u % 5][f] = mk2((lok && cOK0) ? l.x : 0.f,
                                      (lok && cOK1) ? l.y : 0.f);
                } else {
                    L[u % 5][f] = l;
                }
            }
            // 4) output row y from lap rows y-2..y+2 (skip 4 prologue steps)
            if (m > 0 || u >= 4) {
                const float gypM = (!RE || (y + 1 < H)) ? 1.f : 0.f;
                const float gymM = (!RE || (y >= 1)) ? 1.f : 0.f;
#pragma unroll
                for (int f = 0; f < 3; ++f) {
                    const v2f lm2 = L[(u + 1) % 5][f];
                    const v2f lm1 = L[(u + 2) % 5][f];
                    const v2f lc  = L[(u + 3) % 5][f];
                    const v2f lp1 = L[(u + 4) % 5][f];
                    const v2f lp2 = L[u % 5][f];
                    const float A  = dpp_left(lc.y);   // lap(li0-1)
                    const float Bm = dpp_left(lc.x);   // lap(li0-2)
                    const float Bp = dpp_right(lc.x);  // lap(li0+2)
                    const float Cc = dpp_right(lc.y);  // lap(li0+3)
                    const v2f c   = lc;
                    const v2f gx  = mk2(lc.y, Bp) - mk2(A, lc.x);
                    const v2f gy  = lp1 - lm1;
                    const v2f gxp = (mk2(Bp, Cc) - c) * gxpM;
                    const v2f gxm = (c - mk2(Bm, A)) * gxmM;
                    const v2f gyp = (lp2 - c) * gypM;
                    const v2f gym = (c - lm2) * gymM;
                    const v2f hxx = 2.f * gx - gxp - gxm;
                    const v2f hxy = gxp - gxm;
                    const v2f hyy = 2.f * gy - gyp - gym;
                    const v2f ox = 1.f + gx, oy = 1.f + gy;
                    const v2f numer = hxx * oy * oy - 2.f * hxy * (gx * gy)
                                    + hyy * ox * ox;
                    const v2f xx = 1.f + gx * gx + gy * gy;
                    const float rs0 = __builtin_amdgcn_rsqf(xx.x);
                    const float rs1 = __builtin_amdgcn_rsqf(xx.y);
                    const v2f invden = mk2(0.5f * rs0 * rs0 * rs0,
                                           0.5f * rs1 * rs1 * rs1);
                    const v2f curv = numer * invden;
                    const v2f negc = mk2(fmaxf(-curv.x, 0.f),
                                         fmaxf(-curv.y, 0.f)) * aM;
                    sacc[f] += negc;
                    cacc0[f] += (negc.x != 0.f) ? 1u : 0u;
                    cacc1[f] += (negc.y != 0.f) ? 1u : 0u;
                }
            }
        }
    }
}

__global__ __launch_bounds__(NTHREADS, 4)
void curvature_sweep(const float* __restrict__ pred,
                     float* __restrict__ s_ws,
                     unsigned int* __restrict__ c_ws) {
    __shared__ float redS[3][WPB];
    __shared__ unsigned int redC[3][WPB];

    const int strip = blockIdx.x;
    const int b = blockIdx.z;
    const int tid = threadIdx.x;
    const int wv = tid >> 6, lane = tid & 63;
    const int chunk = blockIdx.y * WPB + wv;

    const bool ce = (strip == 0) || (strip == NSTRIPS - 1);
    const bool re = (chunk == 0) || (chunk == NCHUNKS - 1);

    v2f sacc[3] = {mk2(0.f, 0.f), mk2(0.f, 0.f), mk2(0.f, 0.f)};
    unsigned int cacc0[3] = {0u, 0u, 0u};
    unsigned int cacc1[3] = {0u, 0u, 0u};
    if (!ce && !re)
        sweep<false, false>(pred, b, strip, chunk, lane, sacc, cacc0, cacc1);
    else if (ce && !re)
        sweep<true, false>(pred, b, strip, chunk, lane, sacc, cacc0, cacc1);
    else if (!ce && re)
        sweep<false, true>(pred, b, strip, chunk, lane, sacc, cacc0, cacc1);
    else
        sweep<true, true>(pred, b, strip, chunk, lane, sacc, cacc0, cacc1);

    // Wave reduction -> LDS -> one atomic pair per (block, field).
#pragma unroll
    for (int f = 0; f < 3; ++f) {
        float v = sacc[f].x + sacc[f].y;
        unsigned int c = cacc0[f] + cacc1[f];
        for (int off = 32; off > 0; off >>= 1) {
            v += __shfl_xor(v, off, 64);
            c += __shfl_xor(c, off, 64);
        }
        if (lane == 0) { redS[f][wv] = v; redC[f][wv] = c; }
    }
    __syncthreads();
    if (tid < 3) {
        float v = 0.f;
        unsigned int c = 0;
        for (int w2 = 0; w2 < WPB; ++w2) { v += redS[tid][w2]; c += redC[tid][w2]; }
        atomicAdd(&s_ws[b * 3 + tid], v);
        atomicAdd(&c_ws[b * 3 + tid], c);
    }
}

__global__ void finalize_kernel(const float* __restrict__ s_ws,
                                const unsigned int* __restrict__ c_ws,
                                float* __restrict__ out) {
    const int lane = threadIdx.x;
    float v = 0.f;
    if (lane < 24) {
        const float s = s_ws[lane];
        const unsigned int c = c_ws[lane];
        v = (c > 0) ? s / (float)c : 0.f;  // max(c,1)==c when c>0
    }
    for (int off = 32; off > 0; off >>= 1) v += __shfl_down(v, off, 64);
    if (lane == 0) out[0] = v;
}

extern "C" void kernel_launch(void* const* d_in, const int* in_sizes, int n_in,
                              void* d_out, int out_size, void* d_ws, size_t ws_size,
                              hipStream_t stream) {
    const float* pred = (const float*)d_in[0];
    float* s_ws = (float*)d_ws;
    unsigned int* c_ws = (unsigned int*)((char*)d_ws + 24 * sizeof(float));
    float* out = (float*)d_out;

    hipLaunchKernelGGL(zero_ws_kernel, dim3(1), dim3(64), 0, stream,
                       (unsigned int*)d_ws);
    dim3 grid(NSTRIPS, NCHUNKS / WPB, B);
    hipLaunchKernelGGL(curvature_sweep, grid, dim3(NTHREADS), 0, stream,
                       pred, s_ws, c_ws);
    hipLaunchKernelGGL(finalize_kernel, dim3(1), dim3(64), 0, stream,
                       s_ws, c_ws, out);
}